// Round 3
// baseline (223.314 us; speedup 1.0000x reference)
//
#include <hip/hip_runtime.h>

#define B_ 64
#define S_ 512
#define H_ 768
#define L_ 9
#define EMP 12                  // padded emission row stride (floats)
#define NCH 64                  // chunks per batch (8 timesteps each)
#define CVEC 21                 // float4 records per chunk matrix (84 floats)

// ---------------------------------------------------------------------------
// Kernel A: emissions = hidden @ W + b, layout em[t][b][EMP], masked rows skipped
// ---------------------------------------------------------------------------
__global__ __launch_bounds__(256) void emis_kernel(
    const float* __restrict__ hidden, const float* __restrict__ W,
    const float* __restrict__ bias, const int* __restrict__ lengths,
    float* __restrict__ em)
{
    const int lane = threadIdx.x & 63;
    const int wave = (blockIdx.x << 2) + (threadIdx.x >> 6);
    const int row0 = wave << 2;              // 4 consecutive rows, same batch
    const int b = row0 >> 9;
    int len = lengths[b]; if (len < 1) len = 1;
    const int s0 = row0 & 511;
    if (s0 >= len) return;                   // all 4 rows masked -> skip W load

    // W columns for this lane's k-set: k = 256*j + 4*lane + d
    float Wreg[12][9];
    #pragma unroll
    for (int j = 0; j < 3; ++j)
        #pragma unroll
        for (int d = 0; d < 4; ++d) {
            const int k = 256 * j + 4 * lane + d;
            #pragma unroll
            for (int l = 0; l < 9; ++l)
                Wreg[j * 4 + d][l] = W[k * 9 + l];
        }
    const float bl = (lane < 9) ? bias[lane] : 0.0f;

    #pragma unroll
    for (int rr = 0; rr < 4; ++rr) {
        const int s = s0 + rr;
        if (s >= len) continue;
        const int row = row0 + rr;

        const float4* h4 = (const float4*)(hidden + (size_t)row * H_);
        float acc[9];
        #pragma unroll
        for (int l = 0; l < 9; ++l) acc[l] = 0.0f;

        #pragma unroll
        for (int j = 0; j < 3; ++j) {
            float4 h = h4[j * 64 + lane];
            const float* hp = &h.x;
            #pragma unroll
            for (int d = 0; d < 4; ++d) {
                const float hv = hp[d];
                #pragma unroll
                for (int l = 0; l < 9; ++l)
                    acc[l] = fmaf(hv, Wreg[j * 4 + d][l], acc[l]);
            }
        }
        #pragma unroll
        for (int off = 32; off >= 1; off >>= 1)
            #pragma unroll
            for (int l = 0; l < 9; ++l)
                acc[l] += __shfl_xor(acc[l], off, 64);

        float v = acc[0];
        #pragma unroll
        for (int l = 1; l < 9; ++l)
            if (lane == l) v = acc[l];
        if (lane < 9)
            em[(size_t)(s * 64 + b) * EMP + lane] = v + bl;
    }
}

// ---------------------------------------------------------------------------
// Kernel B: per-(batch,chunk) 9x9 transfer-matrix product (8 timesteps/chunk).
// Block = chunk c, lane = batch b.  ROLLED step loop (I$-warm body).
// Dead chunks (t0 >= len) are never read downstream -> no identity write.
// Cm layout: float4 [(c*CVEC + q)*64 + b]; record = 81 matrix + logscale + pad.
// ---------------------------------------------------------------------------
__global__ __launch_bounds__(64, 1) void chunk_kernel(
    const float* __restrict__ em, const float* __restrict__ trans,
    const int* __restrict__ lengths, float4* __restrict__ Cm4)
{
    const int b = threadIdx.x;
    const int c = blockIdx.x;
    int len = lengths[b]; if (len < 1) len = 1;
    const int t0 = 8 * c + 1;

    // whole wave dead -> nothing downstream ever reads these chunks
    if (__ballot(t0 < len) == 0ULL) return;

    float P[81];
    #pragma unroll
    for (int m = 0; m < 81; ++m) P[m] = __expf(trans[m]);

    float A[81];
    #pragma unroll
    for (int i = 0; i < 9; ++i)
        #pragma unroll
        for (int j = 0; j < 9; ++j)
            A[i * 9 + j] = (i == j) ? 1.0f : 0.0f;

    const float* ep = em + (size_t)(t0 * 64 + b) * EMP;

    if (t0 < len) {
        const float4* p = (const float4*)ep;
        float4 v0 = p[0], v1 = p[1], v2 = p[2];
        float e[9] = { __expf(v0.x), __expf(v0.y), __expf(v0.z), __expf(v0.w),
                       __expf(v1.x), __expf(v1.y), __expf(v1.z), __expf(v1.w),
                       __expf(v2.x) };
        #pragma unroll
        for (int i = 0; i < 9; ++i)
            #pragma unroll
            for (int j = 0; j < 9; ++j)
                A[i * 9 + j] = P[i * 9 + j] * e[j];
    }

    #pragma unroll 1
    for (int s = 1; s < 8; ++s) {
        const int t = t0 + s;
        ep += 64 * EMP;
        if (t < len) {
            const float4* p = (const float4*)ep;
            float4 v0 = p[0], v1 = p[1], v2 = p[2];
            float e[9] = { __expf(v0.x), __expf(v0.y), __expf(v0.z), __expf(v0.w),
                           __expf(v1.x), __expf(v1.y), __expf(v1.z), __expf(v1.w),
                           __expf(v2.x) };
            #pragma unroll
            for (int i = 0; i < 9; ++i) {
                float n0, n1, n2, n3, n4, n5, n6, n7, n8;
                const float a0=A[i*9+0], a1=A[i*9+1], a2=A[i*9+2], a3=A[i*9+3],
                            a4=A[i*9+4], a5=A[i*9+5], a6=A[i*9+6], a7=A[i*9+7],
                            a8=A[i*9+8];
                #pragma unroll
                for (int j = 0; j < 9; ++j) {
                    float sum = a0 * P[0*9+j];
                    sum = fmaf(a1, P[1*9+j], sum);
                    sum = fmaf(a2, P[2*9+j], sum);
                    sum = fmaf(a3, P[3*9+j], sum);
                    sum = fmaf(a4, P[4*9+j], sum);
                    sum = fmaf(a5, P[5*9+j], sum);
                    sum = fmaf(a6, P[6*9+j], sum);
                    sum = fmaf(a7, P[7*9+j], sum);
                    sum = fmaf(a8, P[8*9+j], sum);
                    switch (j) {            // delay writeback until row done
                        case 0: n0 = sum * e[0]; break;
                        case 1: n1 = sum * e[1]; break;
                        case 2: n2 = sum * e[2]; break;
                        case 3: n3 = sum * e[3]; break;
                        case 4: n4 = sum * e[4]; break;
                        case 5: n5 = sum * e[5]; break;
                        case 6: n6 = sum * e[6]; break;
                        case 7: n7 = sum * e[7]; break;
                        case 8: n8 = sum * e[8]; break;
                    }
                }
                A[i*9+0]=n0; A[i*9+1]=n1; A[i*9+2]=n2; A[i*9+3]=n3;
                A[i*9+4]=n4; A[i*9+5]=n5; A[i*9+6]=n6; A[i*9+7]=n7; A[i*9+8]=n8;
            }
        }
    }

    float mx = A[0];
    #pragma unroll
    for (int m = 1; m < 81; ++m) mx = fmaxf(mx, A[m]);
    const float r = 1.0f / mx;
    const float lg = __logf(mx);

    #pragma unroll
    for (int q = 0; q < 20; ++q) {
        float4 v;
        v.x = A[4*q+0] * r; v.y = A[4*q+1] * r;
        v.z = A[4*q+2] * r; v.w = A[4*q+3] * r;
        Cm4[((size_t)c * CVEC + q) * 64 + b] = v;
    }
    float4 vt; vt.x = A[80] * r; vt.y = lg; vt.z = 0.0f; vt.w = 0.0f;
    Cm4[((size_t)c * CVEC + 20) * 64 + b] = vt;
}

// ---------------------------------------------------------------------------
// Kernel C: block = batch. Wave 0: alpha scan over ACTIVE chunk matrices only
// (double-buffered). Wave 1: gold-path numerator (lane-strided over t).
// ---------------------------------------------------------------------------
#define LOADC(dst, cc)                                                        \
    do {                                                                      \
        _Pragma("unroll")                                                     \
        for (int q = 0; q < 21; ++q) {                                        \
            float4 v = Cm4[((size_t)(cc) * CVEC + q) * 64 + b];               \
            dst[4*q+0] = v.x; dst[4*q+1] = v.y;                               \
            dst[4*q+2] = v.z; dst[4*q+3] = v.w;                               \
        }                                                                     \
    } while (0)

#define STEPC(Cf)                                                             \
    do {                                                                      \
        float an[9];                                                          \
        _Pragma("unroll")                                                     \
        for (int j = 0; j < 9; ++j) {                                         \
            float s = alpha[0] * Cf[j];                                       \
            _Pragma("unroll")                                                 \
            for (int i = 1; i < 9; ++i) s = fmaf(alpha[i], Cf[i*9+j], s);     \
            an[j] = s;                                                        \
        }                                                                     \
        float m2 = an[0];                                                     \
        _Pragma("unroll")                                                     \
        for (int j = 1; j < 9; ++j) m2 = fmaxf(m2, an[j]);                    \
        logZ += Cf[81] + __logf(m2);                                          \
        const float rr_ = 1.0f / m2;                                          \
        _Pragma("unroll")                                                     \
        for (int j = 0; j < 9; ++j) alpha[j] = an[j] * rr_;                   \
    } while (0)

__global__ __launch_bounds__(128, 1) void final_kernel(
    const float* __restrict__ em, const float4* __restrict__ Cm4,
    const int* __restrict__ labels, const int* __restrict__ lengths,
    const float* __restrict__ start_t, const float* __restrict__ trans,
    const float* __restrict__ end_t, float* __restrict__ out)
{
    const int b = blockIdx.x;
    const int wid = threadIdx.x >> 6, lane = threadIdx.x & 63;
    int len = lengths[b]; if (len < 1) len = 1;

    if (wid == 0) {
        // ---- denominator: alpha0 then scan over active chunks ----
        const float4* e0 = (const float4*)(em + (size_t)b * EMP);
        float4 v0 = e0[0], v1 = e0[1], v2 = e0[2];
        float al[9] = { v0.x + start_t[0], v0.y + start_t[1], v0.z + start_t[2],
                        v0.w + start_t[3], v1.x + start_t[4], v1.y + start_t[5],
                        v1.z + start_t[6], v1.w + start_t[7], v2.x + start_t[8] };
        float m0 = al[0];
        #pragma unroll
        for (int j = 1; j < 9; ++j) m0 = fmaxf(m0, al[j]);
        float alpha[9];
        #pragma unroll
        for (int j = 0; j < 9; ++j) alpha[j] = __expf(al[j] - m0);
        float logZ = m0;

        const int nch = (len - 1 + 7) >> 3;      // active chunks for this batch
        float Ca[84], Cb[84];
        if (nch > 0) {
            LOADC(Ca, 0);
            #pragma unroll 1
            for (int c = 0; c < nch; c += 2) {
                const bool more1 = (c + 1 < nch);
                if (more1) LOADC(Cb, c + 1);
                STEPC(Ca);
                if (!more1) break;
                if (c + 2 < nch) LOADC(Ca, c + 2);
                STEPC(Cb);
            }
        }

        float ev = 0.0f;
        #pragma unroll
        for (int j = 0; j < 9; ++j) ev = fmaf(alpha[j], __expf(end_t[j]), ev);
        if (lane == 0) atomicAdd(out, logZ + __logf(ev));
    } else {
        // ---- numerator ----
        const int* lab = labels + (size_t)b * S_;
        float part = 0.0f;
        for (int t = 1 + lane; t < len; t += 64) {
            const int tp = lab[t - 1], tc = lab[t];
            part += trans[tp * 9 + tc] + em[(size_t)(t * 64 + b) * EMP + tc];
        }
        #pragma unroll
        for (int off = 32; off >= 1; off >>= 1) part += __shfl_xor(part, off, 64);
        if (lane == 0) {
            const int l0 = lab[0], le = lab[len - 1];
            const float num = start_t[l0] + em[(size_t)b * EMP + l0] + part + end_t[le];
            atomicAdd(out, -num);
        }
    }
}

// ---------------------------------------------------------------------------
extern "C" void kernel_launch(void* const* d_in, const int* in_sizes, int n_in,
                              void* d_out, int out_size, void* d_ws, size_t ws_size,
                              hipStream_t stream)
{
    (void)in_sizes; (void)n_in; (void)out_size; (void)ws_size;
    const float* hidden  = (const float*)d_in[0];
    const float* W       = (const float*)d_in[1];
    const float* bias    = (const float*)d_in[2];
    const float* start_t = (const float*)d_in[3];
    const float* trans   = (const float*)d_in[4];
    const float* end_t   = (const float*)d_in[5];
    const int*   labels  = (const int*)d_in[6];
    const int*   lengths = (const int*)d_in[7];

    float*  em  = (float*)d_ws;                       // 512*64*12 floats
    float4* Cm4 = (float4*)(em + (size_t)S_ * 64 * EMP);
    float*  out = (float*)d_out;

    hipMemsetAsync(out, 0, sizeof(float), stream);
    emis_kernel<<<2048, 256, 0, stream>>>(hidden, W, bias, lengths, em);
    chunk_kernel<<<NCH, 64, 0, stream>>>(em, trans, lengths, Cm4);
    final_kernel<<<B_, 128, 0, stream>>>(em, Cm4, labels, lengths,
                                         start_t, trans, end_t, out);
}

// Round 4
// 72.066 us; speedup vs baseline: 3.0987x; 3.0987x over previous
//
#include <hip/hip_runtime.h>

#define B_ 64
#define S_ 512
#define H_ 768
#define L_ 9
#define EMP 12                  // padded emission row stride (floats)
#define NCH 64                  // chunks per batch (8 timesteps each)
#define CVEC 21                 // float4 records per chunk matrix (84 floats)

// ---------------------------------------------------------------------------
// Kernel A: emissions = hidden @ W + b, layout em[t][b][EMP], masked rows skipped
// Also zeroes out[0] (runs before the scan kernel in stream order).
// ---------------------------------------------------------------------------
__global__ __launch_bounds__(256) void emis_kernel(
    const float* __restrict__ hidden, const float* __restrict__ W,
    const float* __restrict__ bias, const int* __restrict__ lengths,
    float* __restrict__ em, float* __restrict__ out)
{
    if (blockIdx.x == 0 && threadIdx.x == 0) out[0] = 0.0f;

    const int lane = threadIdx.x & 63;
    const int wave = (blockIdx.x << 2) + (threadIdx.x >> 6);
    const int row0 = wave << 2;              // 4 consecutive rows, same batch
    const int b = row0 >> 9;
    int len = lengths[b]; if (len < 1) len = 1;
    const int s0 = row0 & 511;
    if (s0 >= len) return;                   // all 4 rows masked -> skip W load

    // W columns for this lane's k-set: k = 256*j + 4*lane + d
    float Wreg[12][9];
    #pragma unroll
    for (int j = 0; j < 3; ++j)
        #pragma unroll
        for (int d = 0; d < 4; ++d) {
            const int k = 256 * j + 4 * lane + d;
            #pragma unroll
            for (int l = 0; l < 9; ++l)
                Wreg[j * 4 + d][l] = W[k * 9 + l];
        }
    const float bl = (lane < 9) ? bias[lane] : 0.0f;

    #pragma unroll
    for (int rr = 0; rr < 4; ++rr) {
        const int s = s0 + rr;
        if (s >= len) continue;
        const int row = row0 + rr;

        const float4* h4 = (const float4*)(hidden + (size_t)row * H_);
        float acc[9];
        #pragma unroll
        for (int l = 0; l < 9; ++l) acc[l] = 0.0f;

        #pragma unroll
        for (int j = 0; j < 3; ++j) {
            float4 h = h4[j * 64 + lane];
            const float* hp = &h.x;
            #pragma unroll
            for (int d = 0; d < 4; ++d) {
                const float hv = hp[d];
                #pragma unroll
                for (int l = 0; l < 9; ++l)
                    acc[l] = fmaf(hv, Wreg[j * 4 + d][l], acc[l]);
            }
        }
        #pragma unroll
        for (int off = 32; off >= 1; off >>= 1)
            #pragma unroll
            for (int l = 0; l < 9; ++l)
                acc[l] += __shfl_xor(acc[l], off, 64);

        float v = acc[0];
        #pragma unroll
        for (int l = 1; l < 9; ++l)
            if (lane == l) v = acc[l];
        if (lane < 9)
            em[(size_t)(s * 64 + b) * EMP + lane] = v + bl;
    }
}

// ---------------------------------------------------------------------------
// Kernel B: per-(batch,chunk) 9x9 transfer-matrix product (8 timesteps/chunk).
// Block = chunk c, lane = batch b.  Rolled step loop.  Dead chunks write
// identity (so the scan may read any chunk index < 64 safely).
// Cm layout: float4 [(c*CVEC + q)*64 + b]; record = 81 matrix + logscale + pad.
// ---------------------------------------------------------------------------
__global__ __launch_bounds__(64, 1) void chunk_kernel(
    const float* __restrict__ em, const float* __restrict__ trans,
    const int* __restrict__ lengths, float4* __restrict__ Cm4)
{
    const int b = threadIdx.x;
    const int c = blockIdx.x;
    int len = lengths[b]; if (len < 1) len = 1;
    const int t0 = 8 * c + 1;

    float P[81];
    #pragma unroll
    for (int m = 0; m < 81; ++m) P[m] = __expf(trans[m]);

    float A[81];
    #pragma unroll
    for (int i = 0; i < 9; ++i)
        #pragma unroll
        for (int j = 0; j < 9; ++j)
            A[i * 9 + j] = (i == j) ? 1.0f : 0.0f;

    const float* ep = em + (size_t)(t0 * 64 + b) * EMP;

    if (t0 < len) {
        const float4* p = (const float4*)ep;
        float4 v0 = p[0], v1 = p[1], v2 = p[2];
        float e[9] = { __expf(v0.x), __expf(v0.y), __expf(v0.z), __expf(v0.w),
                       __expf(v1.x), __expf(v1.y), __expf(v1.z), __expf(v1.w),
                       __expf(v2.x) };
        #pragma unroll
        for (int i = 0; i < 9; ++i)
            #pragma unroll
            for (int j = 0; j < 9; ++j)
                A[i * 9 + j] = P[i * 9 + j] * e[j];
    }

    #pragma unroll 1
    for (int s = 1; s < 8; ++s) {
        const int t = t0 + s;
        ep += 64 * EMP;
        if (t < len) {
            const float4* p = (const float4*)ep;
            float4 v0 = p[0], v1 = p[1], v2 = p[2];
            float e[9] = { __expf(v0.x), __expf(v0.y), __expf(v0.z), __expf(v0.w),
                           __expf(v1.x), __expf(v1.y), __expf(v1.z), __expf(v1.w),
                           __expf(v2.x) };
            #pragma unroll
            for (int i = 0; i < 9; ++i) {
                float n0, n1, n2, n3, n4, n5, n6, n7, n8;
                const float a0=A[i*9+0], a1=A[i*9+1], a2=A[i*9+2], a3=A[i*9+3],
                            a4=A[i*9+4], a5=A[i*9+5], a6=A[i*9+6], a7=A[i*9+7],
                            a8=A[i*9+8];
                #pragma unroll
                for (int j = 0; j < 9; ++j) {
                    float sum = a0 * P[0*9+j];
                    sum = fmaf(a1, P[1*9+j], sum);
                    sum = fmaf(a2, P[2*9+j], sum);
                    sum = fmaf(a3, P[3*9+j], sum);
                    sum = fmaf(a4, P[4*9+j], sum);
                    sum = fmaf(a5, P[5*9+j], sum);
                    sum = fmaf(a6, P[6*9+j], sum);
                    sum = fmaf(a7, P[7*9+j], sum);
                    sum = fmaf(a8, P[8*9+j], sum);
                    switch (j) {
                        case 0: n0 = sum * e[0]; break;
                        case 1: n1 = sum * e[1]; break;
                        case 2: n2 = sum * e[2]; break;
                        case 3: n3 = sum * e[3]; break;
                        case 4: n4 = sum * e[4]; break;
                        case 5: n5 = sum * e[5]; break;
                        case 6: n6 = sum * e[6]; break;
                        case 7: n7 = sum * e[7]; break;
                        case 8: n8 = sum * e[8]; break;
                    }
                }
                A[i*9+0]=n0; A[i*9+1]=n1; A[i*9+2]=n2; A[i*9+3]=n3;
                A[i*9+4]=n4; A[i*9+5]=n5; A[i*9+6]=n6; A[i*9+7]=n7; A[i*9+8]=n8;
            }
        }
    }

    float mx = A[0];
    #pragma unroll
    for (int m = 1; m < 81; ++m) mx = fmaxf(mx, A[m]);
    const float r = __builtin_amdgcn_rcpf(mx);
    const float lg = __logf(mx);

    #pragma unroll
    for (int q = 0; q < 20; ++q) {
        float4 v;
        v.x = A[4*q+0] * r; v.y = A[4*q+1] * r;
        v.z = A[4*q+2] * r; v.w = A[4*q+3] * r;
        Cm4[((size_t)c * CVEC + q) * 64 + b] = v;
    }
    float4 vt; vt.x = A[80] * r; vt.y = lg; vt.z = 0.0f; vt.w = 0.0f;
    Cm4[((size_t)c * CVEC + 20) * 64 + b] = vt;
}

// ---------------------------------------------------------------------------
// Kernel C: grid = 128 one-wave blocks.
//   blocks 0..63   : denominator scan for batch b = blockIdx
//                    (LDS-staged chunk matrices, double-buffered, no big
//                     register arrays -> spill-proof)
//   blocks 64..127 : gold-path numerator for batch b = blockIdx - 64
// ---------------------------------------------------------------------------
__global__ __launch_bounds__(64, 1) void scan_kernel(
    const float* __restrict__ em, const float4* __restrict__ Cm4,
    const int* __restrict__ labels, const int* __restrict__ lengths,
    const float* __restrict__ start_t, const float* __restrict__ trans,
    const float* __restrict__ end_t, float* __restrict__ out)
{
    __shared__ float4 Cs[2][CVEC];
    const int lane = threadIdx.x;
    const int b = blockIdx.x & 63;
    int len = lengths[b]; if (len < 1) len = 1;

    if (blockIdx.x < 64) {
        // ---- denominator ----
        const float4* e0 = (const float4*)(em + (size_t)b * EMP);
        float4 v0 = e0[0], v1 = e0[1], v2 = e0[2];
        float al[9] = { v0.x + start_t[0], v0.y + start_t[1], v0.z + start_t[2],
                        v0.w + start_t[3], v1.x + start_t[4], v1.y + start_t[5],
                        v1.z + start_t[6], v1.w + start_t[7], v2.x + start_t[8] };
        float m0 = al[0];
        #pragma unroll
        for (int j = 1; j < 9; ++j) m0 = fmaxf(m0, al[j]);
        float alpha[9];
        #pragma unroll
        for (int j = 0; j < 9; ++j) alpha[j] = __expf(al[j] - m0);
        float logZ = m0;

        const int nch = (len + 6) >> 3;          // ceil((len-1)/8), 0..64
        if (nch > 0) {
            float4 r;
            if (lane < CVEC) {
                r = Cm4[(size_t)lane * 64 + b];  // matrix 0
                Cs[0][lane] = r;
                const int c1 = (nch > 1) ? 1 : 0;
                r = Cm4[((size_t)c1 * CVEC + lane) * 64 + b];
            }
            #pragma unroll 1
            for (int c = 0; c < nch; ++c) {
                const float4* Cq = Cs[c & 1];
                float an[9];
                #pragma unroll
                for (int j = 0; j < 9; ++j) an[j] = 0.0f;
                float lg = 0.0f;
                #pragma unroll
                for (int q = 0; q < CVEC; ++q) {
                    float4 v = Cq[q];
                    #pragma unroll
                    for (int d = 0; d < 4; ++d) {
                        const int k = 4 * q + d;
                        if (k < 81) {
                            const int i = k / 9, j = k % 9;
                            const float vv = (d == 0) ? v.x : (d == 1) ? v.y
                                           : (d == 2) ? v.z : v.w;
                            an[j] = fmaf(alpha[i], vv, an[j]);
                        } else if (k == 81) {
                            lg = v.y;
                        }
                    }
                }
                float m2 = an[0];
                #pragma unroll
                for (int j = 1; j < 9; ++j) m2 = fmaxf(m2, an[j]);
                logZ += lg + __logf(m2);
                const float rr = __builtin_amdgcn_rcpf(m2);
                #pragma unroll
                for (int j = 0; j < 9; ++j) alpha[j] = an[j] * rr;

                // stage matrix c+1, prefetch matrix c+2 (indices clamped)
                if (lane < CVEC) {
                    Cs[(c + 1) & 1][lane] = r;
                    const int cn = (c + 2 < nch) ? c + 2 : nch - 1;
                    r = Cm4[((size_t)cn * CVEC + lane) * 64 + b];
                }
            }
        }

        float ev = 0.0f;
        #pragma unroll
        for (int j = 0; j < 9; ++j) ev = fmaf(alpha[j], __expf(end_t[j]), ev);
        if (lane == 0) atomicAdd(out, logZ + __logf(ev));
    } else {
        // ---- numerator ----
        const int* lab = labels + (size_t)b * S_;
        float part = 0.0f;
        for (int t = 1 + lane; t < len; t += 64) {
            const int tp = lab[t - 1], tc = lab[t];
            part += trans[tp * 9 + tc] + em[(size_t)(t * 64 + b) * EMP + tc];
        }
        #pragma unroll
        for (int off = 32; off >= 1; off >>= 1) part += __shfl_xor(part, off, 64);
        if (lane == 0) {
            const int l0 = lab[0], le = lab[len - 1];
            const float num = start_t[l0] + em[(size_t)b * EMP + l0] + part + end_t[le];
            atomicAdd(out, -num);
        }
    }
}

// ---------------------------------------------------------------------------
extern "C" void kernel_launch(void* const* d_in, const int* in_sizes, int n_in,
                              void* d_out, int out_size, void* d_ws, size_t ws_size,
                              hipStream_t stream)
{
    (void)in_sizes; (void)n_in; (void)out_size; (void)ws_size;
    const float* hidden  = (const float*)d_in[0];
    const float* W       = (const float*)d_in[1];
    const float* bias    = (const float*)d_in[2];
    const float* start_t = (const float*)d_in[3];
    const float* trans   = (const float*)d_in[4];
    const float* end_t   = (const float*)d_in[5];
    const int*   labels  = (const int*)d_in[6];
    const int*   lengths = (const int*)d_in[7];

    float*  em  = (float*)d_ws;                       // 512*64*12 floats
    float4* Cm4 = (float4*)(em + (size_t)S_ * 64 * EMP);
    float*  out = (float*)d_out;

    emis_kernel<<<2048, 256, 0, stream>>>(hidden, W, bias, lengths, em, out);
    chunk_kernel<<<NCH, 64, 0, stream>>>(em, trans, lengths, Cm4);
    scan_kernel<<<128, 64, 0, stream>>>(em, Cm4, labels, lengths,
                                        start_t, trans, end_t, out);
}

// Round 5
// 55.019 us; speedup vs baseline: 4.0589x; 1.3099x over previous
//
#include <hip/hip_runtime.h>

#define B_ 64
#define S_ 512
#define H_ 768
#define L_ 9
#define EMP 12                  // padded emission row stride (floats)
#define CH 16                   // timesteps per chunk
#define NCHUNK 32               // chunks per batch
#define CPAD 88                 // floats per chunk record in LDS (16B-aligned)

// ---------------------------------------------------------------------------
// Kernel A: emissions = hidden @ W + b, layout em[b][s][EMP], masked rows
// skipped. 8 rows per wave; W fragment loaded as 27 aligned float4.
// Also zeroes out[0] (runs before the CRF kernel in stream order).
// ---------------------------------------------------------------------------
__global__ __launch_bounds__(256) void emis_kernel(
    const float* __restrict__ hidden, const float* __restrict__ W,
    const float* __restrict__ bias, const int* __restrict__ lengths,
    float* __restrict__ em, float* __restrict__ out)
{
    if (blockIdx.x == 0 && threadIdx.x == 0) out[0] = 0.0f;

    const int lane = threadIdx.x & 63;
    const int wave = (blockIdx.x << 2) + (threadIdx.x >> 6);
    const int row0 = wave << 3;              // 8 consecutive rows, same batch
    const int b = row0 >> 9;
    int len = lengths[b]; if (len < 1) len = 1;
    const int s0 = row0 & 511;
    if (s0 >= len) return;                   // whole wave masked

    // lane's k-set: k = 256*j + 4*lane + d  (j=0..2, d=0..3)
    // W rows k..k+3 are 36 contiguous floats at byte offset 144*(64j+lane):
    // 16B-aligned -> 9 float4 loads per j.
    float Wreg[12][9];
    #pragma unroll
    for (int j = 0; j < 3; ++j) {
        const float4* w4 = (const float4*)(W + (size_t)(256 * j + 4 * lane) * 9);
        float wf[36];
        #pragma unroll
        for (int q = 0; q < 9; ++q) {
            float4 v = w4[q];
            wf[4*q+0] = v.x; wf[4*q+1] = v.y; wf[4*q+2] = v.z; wf[4*q+3] = v.w;
        }
        #pragma unroll
        for (int d = 0; d < 4; ++d)
            #pragma unroll
            for (int l = 0; l < 9; ++l)
                Wreg[j * 4 + d][l] = wf[d * 9 + l];
    }
    const float bl = (lane < 9) ? bias[lane] : 0.0f;

    #pragma unroll 1
    for (int rr = 0; rr < 8; ++rr) {
        const int s = s0 + rr;
        if (s >= len) break;                 // uniform across wave
        const int row = row0 + rr;

        const float4* h4 = (const float4*)(hidden + (size_t)row * H_);
        float acc[9];
        #pragma unroll
        for (int l = 0; l < 9; ++l) acc[l] = 0.0f;

        #pragma unroll
        for (int j = 0; j < 3; ++j) {
            float4 h = h4[j * 64 + lane];
            const float* hp = &h.x;
            #pragma unroll
            for (int d = 0; d < 4; ++d) {
                const float hv = hp[d];
                #pragma unroll
                for (int l = 0; l < 9; ++l)
                    acc[l] = fmaf(hv, Wreg[j * 4 + d][l], acc[l]);
            }
        }
        #pragma unroll
        for (int off = 32; off >= 1; off >>= 1)
            #pragma unroll
            for (int l = 0; l < 9; ++l)
                acc[l] += __shfl_xor(acc[l], off, 64);

        float v = acc[0];
        #pragma unroll
        for (int l = 1; l < 9; ++l)
            if (lane == l) v = acc[l];
        if (lane < 9)
            em[(size_t)((b << 9) + s) * EMP + lane] = v + bl;
    }
}

// ---------------------------------------------------------------------------
// Kernel B (fused CRF): one block per batch, 384 threads (6 waves).
//   T in [0,288)  : build chunk matrices row-parallel. T = c*9+i builds row i
//                   of chunk c (16 timesteps, one exact 2^-40 rescale) -> LDS.
//   T in [320,384): gold-path numerator wave.
//   after barrier, wave 0: serial alpha-scan over the <=32 chunk matrices.
// ---------------------------------------------------------------------------
__global__ __launch_bounds__(384, 1) void crf_kernel(
    const float* __restrict__ em, const int* __restrict__ labels,
    const int* __restrict__ lengths, const float* __restrict__ start_t,
    const float* __restrict__ trans, const float* __restrict__ end_t,
    float* __restrict__ out)
{
    __shared__ float Cs[NCHUNK * CPAD];      // 11.3 KiB
    const int T = threadIdx.x;
    const int b = blockIdx.x;
    int len = lengths[b]; if (len < 1) len = 1;

    if (T < 288) {
        const int c = T / 9;
        const int i = T - 9 * c;
        const int t0 = CH * c + 1;

        float P[81];
        #pragma unroll
        for (int m = 0; m < 81; ++m) P[m] = __expf(trans[m]);

        float A[9];
        if (t0 < len) {
            const float4* p = (const float4*)(em + (size_t)((b << 9) + t0) * EMP);
            float4 v0 = p[0], v1 = p[1], v2 = p[2];
            float e[9] = { __expf(v0.x), __expf(v0.y), __expf(v0.z), __expf(v0.w),
                           __expf(v1.x), __expf(v1.y), __expf(v1.z), __expf(v1.w),
                           __expf(v2.x) };
            #pragma unroll
            for (int j = 0; j < 9; ++j) A[j] = P[i * 9 + j] * e[j];
        } else {
            #pragma unroll
            for (int j = 0; j < 9; ++j) A[j] = (i == j) ? 1.0f : 0.0f;
        }

        #pragma unroll 1
        for (int s = 1; s <= 8; ++s) {
            const int t = t0 + s;
            if (t < len) {
                const float4* p = (const float4*)(em + (size_t)((b << 9) + t) * EMP);
                float4 v0 = p[0], v1 = p[1], v2 = p[2];
                float e[9] = { __expf(v0.x), __expf(v0.y), __expf(v0.z), __expf(v0.w),
                               __expf(v1.x), __expf(v1.y), __expf(v1.z), __expf(v1.w),
                               __expf(v2.x) };
                float nn[9];
                #pragma unroll
                for (int j = 0; j < 9; ++j) {
                    float sum = A[0] * P[0 * 9 + j];
                    #pragma unroll
                    for (int k = 1; k < 9; ++k) sum = fmaf(A[k], P[k * 9 + j], sum);
                    nn[j] = sum * e[j];
                }
                #pragma unroll
                for (int j = 0; j < 9; ++j) A[j] = nn[j];
            }
        }
        #pragma unroll
        for (int j = 0; j < 9; ++j) A[j] *= 0x1p-40f;   // exact; scan adds 40ln2/chunk
        #pragma unroll 1
        for (int s = 9; s < CH; ++s) {
            const int t = t0 + s;
            if (t < len) {
                const float4* p = (const float4*)(em + (size_t)((b << 9) + t) * EMP);
                float4 v0 = p[0], v1 = p[1], v2 = p[2];
                float e[9] = { __expf(v0.x), __expf(v0.y), __expf(v0.z), __expf(v0.w),
                               __expf(v1.x), __expf(v1.y), __expf(v1.z), __expf(v1.w),
                               __expf(v2.x) };
                float nn[9];
                #pragma unroll
                for (int j = 0; j < 9; ++j) {
                    float sum = A[0] * P[0 * 9 + j];
                    #pragma unroll
                    for (int k = 1; k < 9; ++k) sum = fmaf(A[k], P[k * 9 + j], sum);
                    nn[j] = sum * e[j];
                }
                #pragma unroll
                for (int j = 0; j < 9; ++j) A[j] = nn[j];
            }
        }
        #pragma unroll
        for (int j = 0; j < 9; ++j) Cs[c * CPAD + i * 9 + j] = A[j];
    } else if (T >= 320) {
        // ---- numerator ----
        const int lane = T - 320;
        const int* lab = labels + (size_t)b * S_;
        float part = 0.0f;
        for (int t = 1 + lane; t < len; t += 64) {
            const int tp = lab[t - 1], tc = lab[t];
            part += trans[tp * 9 + tc] + em[(size_t)((b << 9) + t) * EMP + tc];
        }
        #pragma unroll
        for (int off = 32; off >= 1; off >>= 1) part += __shfl_xor(part, off, 64);
        if (lane == 0) {
            const int l0 = lab[0], le = lab[len - 1];
            const float num = start_t[l0] + em[(size_t)(b << 9) * EMP + l0]
                            + part + end_t[le];
            atomicAdd(out, -num);
        }
    }
    __syncthreads();

    if (T < 64) {
        // ---- denominator scan (redundant across wave 0's lanes) ----
        const float4* e0 = (const float4*)(em + (size_t)(b << 9) * EMP);
        float4 v0 = e0[0], v1 = e0[1], v2 = e0[2];
        float al[9] = { v0.x + start_t[0], v0.y + start_t[1], v0.z + start_t[2],
                        v0.w + start_t[3], v1.x + start_t[4], v1.y + start_t[5],
                        v1.z + start_t[6], v1.w + start_t[7], v2.x + start_t[8] };
        float m0 = al[0];
        #pragma unroll
        for (int j = 1; j < 9; ++j) m0 = fmaxf(m0, al[j]);
        float alpha[9];
        #pragma unroll
        for (int j = 0; j < 9; ++j) alpha[j] = __expf(al[j] - m0);
        float logZ = m0;

        const int nch = (len + 14) >> 4;     // ceil((len-1)/16), 0..32
        #pragma unroll 1
        for (int c = 0; c < nch; ++c) {
            const float4* Cq = (const float4*)&Cs[c * CPAD];
            float an[9];
            #pragma unroll
            for (int j = 0; j < 9; ++j) an[j] = 0.0f;
            #pragma unroll
            for (int q = 0; q < 20; ++q) {
                float4 v = Cq[q];
                #pragma unroll
                for (int d = 0; d < 4; ++d) {
                    const int k = 4 * q + d;
                    const int ii = k / 9, jj = k - 9 * ii;
                    const float vv = (d == 0) ? v.x : (d == 1) ? v.y
                                   : (d == 2) ? v.z : v.w;
                    an[jj] = fmaf(alpha[ii], vv, an[jj]);
                }
            }
            an[8] = fmaf(alpha[8], Cs[c * CPAD + 80], an[8]);

            float m2 = an[0];
            #pragma unroll
            for (int j = 1; j < 9; ++j) m2 = fmaxf(m2, an[j]);
            logZ += __logf(m2);
            const float rr = __builtin_amdgcn_rcpf(m2);
            #pragma unroll
            for (int j = 0; j < 9; ++j) alpha[j] = an[j] * rr;
        }

        float ev = 0.0f;
        #pragma unroll
        for (int j = 0; j < 9; ++j) ev = fmaf(alpha[j], __expf(end_t[j]), ev);
        if (T == 0) {
            const float den = logZ + __logf(ev)
                            + (float)nch * (40.0f * 0.6931471805599453f);
            atomicAdd(out, den);
        }
    }
}

// ---------------------------------------------------------------------------
extern "C" void kernel_launch(void* const* d_in, const int* in_sizes, int n_in,
                              void* d_out, int out_size, void* d_ws, size_t ws_size,
                              hipStream_t stream)
{
    (void)in_sizes; (void)n_in; (void)out_size; (void)ws_size;
    const float* hidden  = (const float*)d_in[0];
    const float* W       = (const float*)d_in[1];
    const float* bias    = (const float*)d_in[2];
    const float* start_t = (const float*)d_in[3];
    const float* trans   = (const float*)d_in[4];
    const float* end_t   = (const float*)d_in[5];
    const int*   labels  = (const int*)d_in[6];
    const int*   lengths = (const int*)d_in[7];

    float* em  = (float*)d_ws;               // 64*512*12 floats = 1.57 MB
    float* out = (float*)d_out;

    emis_kernel<<<1024, 256, 0, stream>>>(hidden, W, bias, lengths, em, out);
    crf_kernel<<<B_, 384, 0, stream>>>(em, labels, lengths,
                                       start_t, trans, end_t, out);
}

// Round 6
// 50.581 us; speedup vs baseline: 4.4150x; 1.0877x over previous
//
#include <hip/hip_runtime.h>

#define B_ 64
#define S_ 512
#define H_ 768
#define L_ 9
#define EMP 12                  // padded emission row stride in global (floats)
#define CH 16                   // timesteps per chunk
#define NCHUNK 32               // chunks per batch
#define CPAD 88                 // floats per chunk record in LDS (16B-aligned)

// eem LDS offset for timestep t: 16B-aligned, bank-staggered per 16-row group
__device__ __forceinline__ int eoff(int t) { return t * 12 + (t >> 4) * 4; }

// ---------------------------------------------------------------------------
// Kernel A: emissions = hidden @ W + b, layout em[b][s][EMP], masked rows
// skipped. 8 rows per wave; W fragment loaded as aligned float4.
// Also zeroes out[0] (runs before the CRF kernel in stream order).
// ---------------------------------------------------------------------------
__global__ __launch_bounds__(256) void emis_kernel(
    const float* __restrict__ hidden, const float* __restrict__ W,
    const float* __restrict__ bias, const int* __restrict__ lengths,
    float* __restrict__ em, float* __restrict__ out)
{
    if (blockIdx.x == 0 && threadIdx.x == 0) out[0] = 0.0f;

    const int lane = threadIdx.x & 63;
    const int wave = (blockIdx.x << 2) + (threadIdx.x >> 6);
    const int row0 = wave << 3;              // 8 consecutive rows, same batch
    const int b = row0 >> 9;
    int len = lengths[b]; if (len < 1) len = 1;
    const int s0 = row0 & 511;
    if (s0 >= len) return;                   // whole wave masked

    float Wreg[12][9];
    #pragma unroll
    for (int j = 0; j < 3; ++j) {
        const float4* w4 = (const float4*)(W + (size_t)(256 * j + 4 * lane) * 9);
        float wf[36];
        #pragma unroll
        for (int q = 0; q < 9; ++q) {
            float4 v = w4[q];
            wf[4*q+0] = v.x; wf[4*q+1] = v.y; wf[4*q+2] = v.z; wf[4*q+3] = v.w;
        }
        #pragma unroll
        for (int d = 0; d < 4; ++d)
            #pragma unroll
            for (int l = 0; l < 9; ++l)
                Wreg[j * 4 + d][l] = wf[d * 9 + l];
    }
    const float bl = (lane < 9) ? bias[lane] : 0.0f;

    #pragma unroll 1
    for (int rr = 0; rr < 8; ++rr) {
        const int s = s0 + rr;
        if (s >= len) break;                 // uniform across wave
        const int row = row0 + rr;

        const float4* h4 = (const float4*)(hidden + (size_t)row * H_);
        float acc[9];
        #pragma unroll
        for (int l = 0; l < 9; ++l) acc[l] = 0.0f;

        #pragma unroll
        for (int j = 0; j < 3; ++j) {
            float4 h = h4[j * 64 + lane];
            const float* hp = &h.x;
            #pragma unroll
            for (int d = 0; d < 4; ++d) {
                const float hv = hp[d];
                #pragma unroll
                for (int l = 0; l < 9; ++l)
                    acc[l] = fmaf(hv, Wreg[j * 4 + d][l], acc[l]);
            }
        }
        #pragma unroll
        for (int off = 32; off >= 1; off >>= 1)
            #pragma unroll
            for (int l = 0; l < 9; ++l)
                acc[l] += __shfl_xor(acc[l], off, 64);

        float v = acc[0];
        #pragma unroll
        for (int l = 1; l < 9; ++l)
            if (lane == l) v = acc[l];
        if (lane < 9)
            em[(size_t)((b << 9) + s) * EMP + lane] = v + bl;
    }
}

// ---------------------------------------------------------------------------
// Kernel B (fused CRF): one block per batch, 384 threads.
//  phase 0: P=exp(trans) -> LDS (81 floats);  eem=exp(em) -> LDS (all 512 rows,
//           zeros past len). All threads participate.
//  phase 1: T<144: build chunk transfer matrices, 2 chunks/thread (c, c+16),
//           row i. All operands from LDS; ~60 live floats, no big arrays.
//           T>=320: gold-path numerator.
//  phase 2: wave 0: serial alpha-scan over <=32 chunk matrices in LDS.
// ---------------------------------------------------------------------------
__global__ __launch_bounds__(384, 1) void crf_kernel(
    const float* __restrict__ em, const int* __restrict__ labels,
    const int* __restrict__ lengths, const float* __restrict__ start_t,
    const float* __restrict__ trans, const float* __restrict__ end_t,
    float* __restrict__ out)
{
    __shared__ float eem[6288];              // staggered exp(em) rows, 24.6 KiB
    __shared__ float Pl[112];                // exp(trans), rows padded to 12
    __shared__ float Cs[NCHUNK * CPAD];      // chunk matrices, 11 KiB
    const int T = threadIdx.x;
    const int b = blockIdx.x;
    int len = lengths[b]; if (len < 1) len = 1;

    // ---- phase 0: shared tables ----
    if (T < 81) {
        const int k = T / 9, j = T - 9 * k;
        Pl[k * 12 + j] = __expf(trans[T]);
    }
    #pragma unroll
    for (int r = 0; r < 2; ++r) {
        const int t = T + 384 * r;
        if (t < 512) {
            const int o = eoff(t);
            if (t < len) {
                const float4* p = (const float4*)(em + (size_t)((b << 9) + t) * EMP);
                float4 v0 = p[0], v1 = p[1], v2 = p[2];
                float4 w0 = { __expf(v0.x), __expf(v0.y), __expf(v0.z), __expf(v0.w) };
                float4 w1 = { __expf(v1.x), __expf(v1.y), __expf(v1.z), __expf(v1.w) };
                *(float4*)(eem + o) = w0;
                *(float4*)(eem + o + 4) = w1;
                eem[o + 8] = __expf(v2.x);
            } else {
                const float4 z = { 0.0f, 0.0f, 0.0f, 0.0f };
                *(float4*)(eem + o) = z;
                *(float4*)(eem + o + 4) = z;
                eem[o + 8] = 0.0f;
            }
        }
    }
    __syncthreads();

    // ---- phase 1 ----
    if (T < 144) {
        const int c0 = T / 9;                // 0..15; handles chunks c0, c0+16
        const int i  = T - 9 * c0;
        float A0[9], A1[9];
        #pragma unroll
        for (int j = 0; j < 9; ++j) { A0[j] = (i == j) ? 1.0f : 0.0f; A1[j] = A0[j]; }
        const int ta0 = CH * c0 + 1;
        const int tb0 = ta0 + 256;

        #pragma unroll 1
        for (int s = 0; s < CH; ++s) {
            const int ta = ta0 + s, tb = tb0 + s;
            const int oa = eoff(ta), ob = eoff(tb);
            float4 ea0 = *(const float4*)(eem + oa);
            float4 ea1 = *(const float4*)(eem + oa + 4);
            const float ea8 = eem[oa + 8];
            float4 eb0 = *(const float4*)(eem + ob);
            float4 eb1 = *(const float4*)(eem + ob + 4);
            const float eb8 = eem[ob + 8];
            const float ea[9] = { ea0.x, ea0.y, ea0.z, ea0.w,
                                  ea1.x, ea1.y, ea1.z, ea1.w, ea8 };
            const float eb[9] = { eb0.x, eb0.y, eb0.z, eb0.w,
                                  eb1.x, eb1.y, eb1.z, eb1.w, eb8 };

            float an0[9], an1[9];
            #pragma unroll
            for (int j = 0; j < 9; ++j) { an0[j] = 0.0f; an1[j] = 0.0f; }
            #pragma unroll
            for (int k = 0; k < 9; ++k) {
                float4 p0 = *(const float4*)(Pl + k * 12);
                float4 p1 = *(const float4*)(Pl + k * 12 + 4);
                const float p8 = Pl[k * 12 + 8];
                const float pr[9] = { p0.x, p0.y, p0.z, p0.w,
                                      p1.x, p1.y, p1.z, p1.w, p8 };
                const float a0k = A0[k], a1k = A1[k];
                #pragma unroll
                for (int j = 0; j < 9; ++j) {
                    an0[j] = fmaf(a0k, pr[j], an0[j]);
                    an1[j] = fmaf(a1k, pr[j], an1[j]);
                }
            }
            const bool la = (ta < len), lb = (tb < len);
            #pragma unroll
            for (int j = 0; j < 9; ++j) {
                A0[j] = la ? an0[j] * ea[j] : A0[j];
                A1[j] = lb ? an1[j] * eb[j] : A1[j];
            }
            if (s == 7) {                    // exact 2^-40; scan adds 40ln2/chunk
                #pragma unroll
                for (int j = 0; j < 9; ++j) { A0[j] *= 0x1p-40f; A1[j] *= 0x1p-40f; }
            }
        }
        #pragma unroll
        for (int j = 0; j < 9; ++j) {
            Cs[c0 * CPAD + i * 9 + j] = A0[j];
            Cs[(c0 + 16) * CPAD + i * 9 + j] = A1[j];
        }
    } else if (T >= 320) {
        // ---- numerator ----
        const int lane = T - 320;
        const int* lab = labels + (size_t)b * S_;
        float part = 0.0f;
        for (int t = 1 + lane; t < len; t += 64) {
            const int tp = lab[t - 1], tc = lab[t];
            part += trans[tp * 9 + tc] + em[(size_t)((b << 9) + t) * EMP + tc];
        }
        #pragma unroll
        for (int off = 32; off >= 1; off >>= 1) part += __shfl_xor(part, off, 64);
        if (lane == 0) {
            const int l0 = lab[0], le = lab[len - 1];
            const float num = start_t[l0] + em[(size_t)(b << 9) * EMP + l0]
                            + part + end_t[le];
            atomicAdd(out, -num);
        }
    }
    __syncthreads();

    // ---- phase 2: denominator scan (redundant across wave 0's lanes) ----
    if (T < 64) {
        const float4* e0 = (const float4*)(em + (size_t)(b << 9) * EMP);
        float4 v0 = e0[0], v1 = e0[1], v2 = e0[2];
        float al[9] = { v0.x + start_t[0], v0.y + start_t[1], v0.z + start_t[2],
                        v0.w + start_t[3], v1.x + start_t[4], v1.y + start_t[5],
                        v1.z + start_t[6], v1.w + start_t[7], v2.x + start_t[8] };
        float m0 = al[0];
        #pragma unroll
        for (int j = 1; j < 9; ++j) m0 = fmaxf(m0, al[j]);
        float alpha[9];
        #pragma unroll
        for (int j = 0; j < 9; ++j) alpha[j] = __expf(al[j] - m0);
        float logZ = m0;

        const int nch = (len + 14) >> 4;     // ceil((len-1)/16), 0..32
        #pragma unroll 1
        for (int c = 0; c < nch; ++c) {
            const float4* Cq = (const float4*)&Cs[c * CPAD];
            float an[9];
            #pragma unroll
            for (int j = 0; j < 9; ++j) an[j] = 0.0f;
            #pragma unroll
            for (int q = 0; q < 20; ++q) {
                float4 v = Cq[q];
                #pragma unroll
                for (int d = 0; d < 4; ++d) {
                    const int k = 4 * q + d;
                    const int ii = k / 9, jj = k - 9 * ii;
                    const float vv = (d == 0) ? v.x : (d == 1) ? v.y
                                   : (d == 2) ? v.z : v.w;
                    an[jj] = fmaf(alpha[ii], vv, an[jj]);
                }
            }
            an[8] = fmaf(alpha[8], Cs[c * CPAD + 80], an[8]);

            float m2 = an[0];
            #pragma unroll
            for (int j = 1; j < 9; ++j) m2 = fmaxf(m2, an[j]);
            logZ += __logf(m2);
            const float rr = __builtin_amdgcn_rcpf(m2);
            #pragma unroll
            for (int j = 0; j < 9; ++j) alpha[j] = an[j] * rr;
        }

        float ev = 0.0f;
        #pragma unroll
        for (int j = 0; j < 9; ++j) ev = fmaf(alpha[j], __expf(end_t[j]), ev);
        if (T == 0) {
            const float den = logZ + __logf(ev)
                            + (float)nch * (40.0f * 0.6931471805599453f);
            atomicAdd(out, den);
        }
    }
}

// ---------------------------------------------------------------------------
extern "C" void kernel_launch(void* const* d_in, const int* in_sizes, int n_in,
                              void* d_out, int out_size, void* d_ws, size_t ws_size,
                              hipStream_t stream)
{
    (void)in_sizes; (void)n_in; (void)out_size; (void)ws_size;
    const float* hidden  = (const float*)d_in[0];
    const float* W       = (const float*)d_in[1];
    const float* bias    = (const float*)d_in[2];
    const float* start_t = (const float*)d_in[3];
    const float* trans   = (const float*)d_in[4];
    const float* end_t   = (const float*)d_in[5];
    const int*   labels  = (const int*)d_in[6];
    const int*   lengths = (const int*)d_in[7];

    float* em  = (float*)d_ws;               // 64*512*12 floats = 1.57 MB
    float* out = (float*)d_out;

    emis_kernel<<<1024, 256, 0, stream>>>(hidden, W, bias, lengths, em, out);
    crf_kernel<<<B_, 384, 0, stream>>>(em, labels, lengths,
                                       start_t, trans, end_t, out);
}

// Round 7
// 44.729 us; speedup vs baseline: 4.9926x; 1.1308x over previous
//
#include <hip/hip_runtime.h>

#define B_ 64
#define S_ 512
#define H_ 768
#define L_ 9
#define EMP 12                  // padded emission row stride in global (floats)
#define CH 16                   // timesteps per chunk
#define NCHUNK 32               // chunks per batch
#define CPAD 88                 // floats per chunk record in LDS (16B-aligned)

// eem LDS offset for timestep t: 16B-aligned, bank-staggered per 16-row group
__device__ __forceinline__ int eoff(int t) { return t * 12 + (t >> 4) * 4; }

// DPP add: v += lane-shifted v (invalid/masked lanes contribute 0 since old=0)
#define DPPADD(v, ctrl, rm)                                                   \
    v += __int_as_float(__builtin_amdgcn_update_dpp(                          \
            0, __float_as_int(v), ctrl, rm, 0xf, false))

// canonical gfx9 wave64 sum: result lands in lane 63 (VALU only, no LDS)
#define REDUCE64(v)                                                           \
    do {                                                                      \
        DPPADD(v, 0x111, 0xf);   /* row_shr:1  */                             \
        DPPADD(v, 0x112, 0xf);   /* row_shr:2  */                             \
        DPPADD(v, 0x114, 0xf);   /* row_shr:4  */                             \
        DPPADD(v, 0x118, 0xf);   /* row_shr:8  */                             \
        DPPADD(v, 0x142, 0xa);   /* row_bcast:15 -> rows 1,3 */               \
        DPPADD(v, 0x143, 0xc);   /* row_bcast:31 -> rows 2,3 */               \
    } while (0)

// ---------------------------------------------------------------------------
// Kernel A: emissions = hidden @ W + b, layout em[b][s][EMP].
// 8 rows/wave, W fragment (108 floats) in VGPRs, DPP reduce (no LDS),
// lane 63 stores the 9 outputs. Waves fully past len exit before W load.
// Also zeroes out[0] (runs before the CRF kernel in stream order).
// ---------------------------------------------------------------------------
__global__ __launch_bounds__(256) void emis_kernel(
    const float* __restrict__ hidden, const float* __restrict__ W,
    const float* __restrict__ bias, const int* __restrict__ lengths,
    float* __restrict__ em, float* __restrict__ out)
{
    if (blockIdx.x == 0 && threadIdx.x == 0) out[0] = 0.0f;

    const int lane = threadIdx.x & 63;
    const int wave = (blockIdx.x << 2) + (threadIdx.x >> 6);
    const int row0 = wave << 3;              // 8 consecutive rows, same batch
    const int b = row0 >> 9;
    int len = lengths[b]; if (len < 1) len = 1;
    const int s0 = row0 & 511;
    if (s0 >= len) return;                   // whole wave masked

    // lane's k-set: k = 256*j + 4*lane + d  -> 27 aligned float4 of W
    float Wreg[12][9];
    #pragma unroll
    for (int j = 0; j < 3; ++j) {
        const float4* w4 = (const float4*)(W + (size_t)(256 * j + 4 * lane) * 9);
        float wf[36];
        #pragma unroll
        for (int q = 0; q < 9; ++q) {
            float4 v = w4[q];
            wf[4*q+0] = v.x; wf[4*q+1] = v.y; wf[4*q+2] = v.z; wf[4*q+3] = v.w;
        }
        #pragma unroll
        for (int d = 0; d < 4; ++d)
            #pragma unroll
            for (int l = 0; l < 9; ++l)
                Wreg[j * 4 + d][l] = wf[d * 9 + l];
    }
    float bl[9];
    #pragma unroll
    for (int l = 0; l < 9; ++l) bl[l] = bias[l];   // uniform -> scalar loads

    const float4* h4 = (const float4*)(hidden + (size_t)row0 * H_);

    #pragma unroll 1
    for (int p = 0; p < 4; ++p) {            // 4 pairs of rows
        const int sA = s0 + 2 * p;
        if (sA >= len) break;                // uniform across wave

        // issue both rows' loads up front (6 float4 in flight)
        float4 hA0 = h4[(2*p    ) * 192 + lane];
        float4 hA1 = h4[(2*p    ) * 192 +  64 + lane];
        float4 hA2 = h4[(2*p    ) * 192 + 128 + lane];
        float4 hB0 = h4[(2*p + 1) * 192 + lane];
        float4 hB1 = h4[(2*p + 1) * 192 +  64 + lane];
        float4 hB2 = h4[(2*p + 1) * 192 + 128 + lane];

        #pragma unroll
        for (int half = 0; half < 2; ++half) {
            const float4 h0 = half ? hB0 : hA0;
            const float4 h1 = half ? hB1 : hA1;
            const float4 h2 = half ? hB2 : hA2;
            const float hv[12] = { h0.x, h0.y, h0.z, h0.w,
                                   h1.x, h1.y, h1.z, h1.w,
                                   h2.x, h2.y, h2.z, h2.w };
            float acc[9];
            #pragma unroll
            for (int l = 0; l < 9; ++l) acc[l] = 0.0f;
            #pragma unroll
            for (int j = 0; j < 3; ++j)
                #pragma unroll
                for (int d = 0; d < 4; ++d) {
                    const float h = hv[j * 4 + d];
                    #pragma unroll
                    for (int l = 0; l < 9; ++l)
                        acc[l] = fmaf(h, Wreg[j * 4 + d][l], acc[l]);
                }

            #pragma unroll
            for (int l = 0; l < 9; ++l) REDUCE64(acc[l]);

            const int s = sA + half;
            if (lane == 63 && s < len) {     // lane 63 holds all 9 sums
                float* dst = em + (size_t)((b << 9) + s) * EMP;
                float4 o0 = { acc[0] + bl[0], acc[1] + bl[1],
                              acc[2] + bl[2], acc[3] + bl[3] };
                float4 o1 = { acc[4] + bl[4], acc[5] + bl[5],
                              acc[6] + bl[6], acc[7] + bl[7] };
                *(float4*)dst = o0;
                *(float4*)(dst + 4) = o1;
                dst[8] = acc[8] + bl[8];
            }
        }
    }
}

// ---------------------------------------------------------------------------
// Kernel B (fused CRF): one block per batch, 384 threads.  (unchanged r6)
//  phase 0: P=exp(trans) -> LDS; eem=exp(em) -> LDS (zeros past len).
//  phase 1: T<144: build chunk transfer matrices, 2 chunks/thread, row i.
//           T>=320: gold-path numerator.
//  phase 2: wave 0: serial alpha-scan over <=32 chunk matrices in LDS.
// ---------------------------------------------------------------------------
__global__ __launch_bounds__(384, 1) void crf_kernel(
    const float* __restrict__ em, const int* __restrict__ labels,
    const int* __restrict__ lengths, const float* __restrict__ start_t,
    const float* __restrict__ trans, const float* __restrict__ end_t,
    float* __restrict__ out)
{
    __shared__ float eem[6288];              // staggered exp(em) rows, 24.6 KiB
    __shared__ float Pl[112];                // exp(trans), rows padded to 12
    __shared__ float Cs[NCHUNK * CPAD];      // chunk matrices, 11 KiB
    const int T = threadIdx.x;
    const int b = blockIdx.x;
    int len = lengths[b]; if (len < 1) len = 1;

    // ---- phase 0: shared tables ----
    if (T < 81) {
        const int k = T / 9, j = T - 9 * k;
        Pl[k * 12 + j] = __expf(trans[T]);
    }
    #pragma unroll
    for (int r = 0; r < 2; ++r) {
        const int t = T + 384 * r;
        if (t < 512) {
            const int o = eoff(t);
            if (t < len) {
                const float4* p = (const float4*)(em + (size_t)((b << 9) + t) * EMP);
                float4 v0 = p[0], v1 = p[1], v2 = p[2];
                float4 w0 = { __expf(v0.x), __expf(v0.y), __expf(v0.z), __expf(v0.w) };
                float4 w1 = { __expf(v1.x), __expf(v1.y), __expf(v1.z), __expf(v1.w) };
                *(float4*)(eem + o) = w0;
                *(float4*)(eem + o + 4) = w1;
                eem[o + 8] = __expf(v2.x);
            } else {
                const float4 z = { 0.0f, 0.0f, 0.0f, 0.0f };
                *(float4*)(eem + o) = z;
                *(float4*)(eem + o + 4) = z;
                eem[o + 8] = 0.0f;
            }
        }
    }
    __syncthreads();

    // ---- phase 1 ----
    if (T < 144) {
        const int c0 = T / 9;                // 0..15; handles chunks c0, c0+16
        const int i  = T - 9 * c0;
        float A0[9], A1[9];
        #pragma unroll
        for (int j = 0; j < 9; ++j) { A0[j] = (i == j) ? 1.0f : 0.0f; A1[j] = A0[j]; }
        const int ta0 = CH * c0 + 1;
        const int tb0 = ta0 + 256;

        #pragma unroll 1
        for (int s = 0; s < CH; ++s) {
            const int ta = ta0 + s, tb = tb0 + s;
            const int oa = eoff(ta), ob = eoff(tb);
            float4 ea0 = *(const float4*)(eem + oa);
            float4 ea1 = *(const float4*)(eem + oa + 4);
            const float ea8 = eem[oa + 8];
            float4 eb0 = *(const float4*)(eem + ob);
            float4 eb1 = *(const float4*)(eem + ob + 4);
            const float eb8 = eem[ob + 8];
            const float ea[9] = { ea0.x, ea0.y, ea0.z, ea0.w,
                                  ea1.x, ea1.y, ea1.z, ea1.w, ea8 };
            const float eb[9] = { eb0.x, eb0.y, eb0.z, eb0.w,
                                  eb1.x, eb1.y, eb1.z, eb1.w, eb8 };

            float an0[9], an1[9];
            #pragma unroll
            for (int j = 0; j < 9; ++j) { an0[j] = 0.0f; an1[j] = 0.0f; }
            #pragma unroll
            for (int k = 0; k < 9; ++k) {
                float4 p0 = *(const float4*)(Pl + k * 12);
                float4 p1 = *(const float4*)(Pl + k * 12 + 4);
                const float p8 = Pl[k * 12 + 8];
                const float pr[9] = { p0.x, p0.y, p0.z, p0.w,
                                      p1.x, p1.y, p1.z, p1.w, p8 };
                const float a0k = A0[k], a1k = A1[k];
                #pragma unroll
                for (int j = 0; j < 9; ++j) {
                    an0[j] = fmaf(a0k, pr[j], an0[j]);
                    an1[j] = fmaf(a1k, pr[j], an1[j]);
                }
            }
            const bool la = (ta < len), lb = (tb < len);
            #pragma unroll
            for (int j = 0; j < 9; ++j) {
                A0[j] = la ? an0[j] * ea[j] : A0[j];
                A1[j] = lb ? an1[j] * eb[j] : A1[j];
            }
            if (s == 7) {                    // exact 2^-40; scan adds 40ln2/chunk
                #pragma unroll
                for (int j = 0; j < 9; ++j) { A0[j] *= 0x1p-40f; A1[j] *= 0x1p-40f; }
            }
        }
        #pragma unroll
        for (int j = 0; j < 9; ++j) {
            Cs[c0 * CPAD + i * 9 + j] = A0[j];
            Cs[(c0 + 16) * CPAD + i * 9 + j] = A1[j];
        }
    } else if (T >= 320) {
        // ---- numerator ----
        const int lane = T - 320;
        const int* lab = labels + (size_t)b * S_;
        float part = 0.0f;
        for (int t = 1 + lane; t < len; t += 64) {
            const int tp = lab[t - 1], tc = lab[t];
            part += trans[tp * 9 + tc] + em[(size_t)((b << 9) + t) * EMP + tc];
        }
        #pragma unroll
        for (int off = 32; off >= 1; off >>= 1) part += __shfl_xor(part, off, 64);
        if (lane == 0) {
            const int l0 = lab[0], le = lab[len - 1];
            const float num = start_t[l0] + em[(size_t)(b << 9) * EMP + l0]
                            + part + end_t[le];
            atomicAdd(out, -num);
        }
    }
    __syncthreads();

    // ---- phase 2: denominator scan (redundant across wave 0's lanes) ----
    if (T < 64) {
        const float4* e0 = (const float4*)(em + (size_t)(b << 9) * EMP);
        float4 v0 = e0[0], v1 = e0[1], v2 = e0[2];
        float al[9] = { v0.x + start_t[0], v0.y + start_t[1], v0.z + start_t[2],
                        v0.w + start_t[3], v1.x + start_t[4], v1.y + start_t[5],
                        v1.z + start_t[6], v1.w + start_t[7], v2.x + start_t[8] };
        float m0 = al[0];
        #pragma unroll
        for (int j = 1; j < 9; ++j) m0 = fmaxf(m0, al[j]);
        float alpha[9];
        #pragma unroll
        for (int j = 0; j < 9; ++j) alpha[j] = __expf(al[j] - m0);
        float logZ = m0;

        const int nch = (len + 14) >> 4;     // ceil((len-1)/16), 0..32
        #pragma unroll 1
        for (int c = 0; c < nch; ++c) {
            const float4* Cq = (const float4*)&Cs[c * CPAD];
            float an[9];
            #pragma unroll
            for (int j = 0; j < 9; ++j) an[j] = 0.0f;
            #pragma unroll
            for (int q = 0; q < 20; ++q) {
                float4 v = Cq[q];
                #pragma unroll
                for (int d = 0; d < 4; ++d) {
                    const int k = 4 * q + d;
                    const int ii = k / 9, jj = k - 9 * ii;
                    const float vv = (d == 0) ? v.x : (d == 1) ? v.y
                                   : (d == 2) ? v.z : v.w;
                    an[jj] = fmaf(alpha[ii], vv, an[jj]);
                }
            }
            an[8] = fmaf(alpha[8], Cs[c * CPAD + 80], an[8]);

            float m2 = an[0];
            #pragma unroll
            for (int j = 1; j < 9; ++j) m2 = fmaxf(m2, an[j]);
            logZ += __logf(m2);
            const float rr = __builtin_amdgcn_rcpf(m2);
            #pragma unroll
            for (int j = 0; j < 9; ++j) alpha[j] = an[j] * rr;
        }

        float ev = 0.0f;
        #pragma unroll
        for (int j = 0; j < 9; ++j) ev = fmaf(alpha[j], __expf(end_t[j]), ev);
        if (T == 0) {
            const float den = logZ + __logf(ev)
                            + (float)nch * (40.0f * 0.6931471805599453f);
            atomicAdd(out, den);
        }
    }
}

// ---------------------------------------------------------------------------
extern "C" void kernel_launch(void* const* d_in, const int* in_sizes, int n_in,
                              void* d_out, int out_size, void* d_ws, size_t ws_size,
                              hipStream_t stream)
{
    (void)in_sizes; (void)n_in; (void)out_size; (void)ws_size;
    const float* hidden  = (const float*)d_in[0];
    const float* W       = (const float*)d_in[1];
    const float* bias    = (const float*)d_in[2];
    const float* start_t = (const float*)d_in[3];
    const float* trans   = (const float*)d_in[4];
    const float* end_t   = (const float*)d_in[5];
    const int*   labels  = (const int*)d_in[6];
    const int*   lengths = (const int*)d_in[7];

    float* em  = (float*)d_ws;               // 64*512*12 floats = 1.57 MB
    float* out = (float*)d_out;

    emis_kernel<<<1024, 256, 0, stream>>>(hidden, W, bias, lengths, em, out);
    crf_kernel<<<B_, 384, 0, stream>>>(em, labels, lengths,
                                       start_t, trans, end_t, out);
}

// Round 8
// 33.280 us; speedup vs baseline: 6.7102x; 1.3440x over previous
//
#include <hip/hip_runtime.h>

#define B_ 64
#define S_ 512
#define H_ 768
#define L_ 9
#define EMP 16                  // padded emission row stride in global (floats)
#define CH 16                   // timesteps per chunk
#define NCHUNK 32               // chunks per batch
#define CPAD 88                 // floats per chunk record in LDS (16B-aligned)

typedef __attribute__((ext_vector_type(8))) short bf16x8;
typedef __attribute__((ext_vector_type(4))) float f32x4;

// eem LDS offset for timestep t: 16B-aligned, bank-staggered per 16-row group
__device__ __forceinline__ int eoff(int t) { return t * 12 + (t >> 4) * 4; }

// pack two fp32 -> one u32 of two bf16 (round-to-nearest via +0x8000)
__device__ __forceinline__ unsigned pack_bf16(float lo, float hi) {
    unsigned a = __float_as_uint(lo) + 0x8000u;
    unsigned b = __float_as_uint(hi) + 0x8000u;
    return __builtin_amdgcn_perm(b, a, 0x07060302);  // {b.b23, a.b23}
}

// ---------------------------------------------------------------------------
// Kernel A (MFMA): em[b][s][16] = hidden @ W + b  (cols 9..15 = 0/junk).
// Block = 64 rows (4 waves x 16-row tile), 512 blocks.
// D = W^T * hidden^T  ->  lane l holds em[row0+(l&15)][4*(l>>4) .. +3]
// W pre-packed once per block into LDS as bf16 A-fragments (16 cols, 0-pad).
// Also zeroes out[0] (runs before the CRF kernel in stream order).
// ---------------------------------------------------------------------------
__global__ __launch_bounds__(256) void emis_kernel(
    const float* __restrict__ hidden, const float* __restrict__ W,
    const float* __restrict__ bias, const int* __restrict__ lengths,
    float* __restrict__ em, float* __restrict__ out)
{
    __shared__ float    Wf[H_ * L_];         // fp32 W staged coalesced (27 KB)
    __shared__ unsigned Wl[96 * 16 * 4];     // bf16x8 frags [k8][col] (24 KB)
    __shared__ float    bias16[16];

    const int T = threadIdx.x;
    if (blockIdx.x == 0 && T == 0) out[0] = 0.0f;

    const int row0 = blockIdx.x * 64;
    const int b = row0 >> 9;
    int len = lengths[b]; if (len < 1) len = 1;
    const int s0 = row0 & 511;
    if (s0 >= len) return;                   // whole block masked

    // stage W fp32, coalesced
    #pragma unroll
    for (int i = 0; i < 27; ++i) Wf[T + 256 * i] = W[T + 256 * i];
    if (T < 16) bias16[T] = (T < 9) ? bias[T] : 0.0f;
    __syncthreads();

    // build A-fragment slots: slot = k8*16 + col holds bf16 W[k8*8..+7][col]
    #pragma unroll
    for (int r6 = 0; r6 < 6; ++r6) {
        const int sidx = T + 256 * r6;       // 0..1535
        const int k8 = sidx >> 4, col = sidx & 15;
        unsigned w0 = 0, w1 = 0, w2 = 0, w3 = 0;
        if (col < 9) {
            const float* wp = Wf + (k8 * 8) * 9 + col;
            w0 = pack_bf16(wp[0 * 9], wp[1 * 9]);
            w1 = pack_bf16(wp[2 * 9], wp[3 * 9]);
            w2 = pack_bf16(wp[4 * 9], wp[5 * 9]);
            w3 = pack_bf16(wp[6 * 9], wp[7 * 9]);
        }
        uint4 v = { w0, w1, w2, w3 };
        *(uint4*)&Wl[sidx * 4] = v;
    }
    __syncthreads();

    const int wv = T >> 6, lane = T & 63;
    const int r0 = row0 + wv * 16;           // this wave's 16-row tile
    const int srow = (r0 & 511) + (lane & 15);
    if ((r0 & 511) >= len) return;           // whole tile masked (post-barrier)

    const float* hp = hidden + (size_t)(r0 + (lane & 15)) * H_ + (lane >> 4) * 8;

    f32x4 acc = { 0.0f, 0.0f, 0.0f, 0.0f };
    #pragma unroll
    for (int st = 0; st < 24; ++st) {
        float4 h0 = *(const float4*)(hp + st * 32);
        float4 h1 = *(const float4*)(hp + st * 32 + 4);
        union { unsigned u[4]; bf16x8 v; } bu;
        bu.u[0] = pack_bf16(h0.x, h0.y);
        bu.u[1] = pack_bf16(h0.z, h0.w);
        bu.u[2] = pack_bf16(h1.x, h1.y);
        bu.u[3] = pack_bf16(h1.z, h1.w);
        const bf16x8 af = *(const bf16x8*)&Wl[((st * 4 + (lane >> 4)) * 16
                                              + (lane & 15)) * 4];
        acc = __builtin_amdgcn_mfma_f32_16x16x32_bf16(af, bu.v, acc, 0, 0, 0);
    }

    if (srow < len) {
        const int colb = (lane >> 4) * 4;
        float4 o = { acc[0] + bias16[colb + 0], acc[1] + bias16[colb + 1],
                     acc[2] + bias16[colb + 2], acc[3] + bias16[colb + 3] };
        *(float4*)(em + (size_t)((b << 9) + srow) * EMP + colb) = o;
    }
}

// ---------------------------------------------------------------------------
// Kernel B (fused CRF): one block per batch, 384 threads.
//  phase 0: P=exp(trans) -> LDS; eem=exp(em) -> LDS (zeros past len).
//  phase 1: T<144: build 32 chunk transfer matrices (2 chunks/thread, row i);
//           T>=320: gold-path numerator.
//  phase 2: binary tree product of the 32 matrices (5 levels, adaptive
//           rescale, logs in LDS), then wave 0 applies alpha0 and end_t.
// ---------------------------------------------------------------------------
__global__ __launch_bounds__(384, 1) void crf_kernel(
    const float* __restrict__ em, const int* __restrict__ labels,
    const int* __restrict__ lengths, const float* __restrict__ start_t,
    const float* __restrict__ trans, const float* __restrict__ end_t,
    float* __restrict__ out)
{
    __shared__ float eem[6288];              // staggered exp(em) rows, 24.6 KiB
    __shared__ float Pl[112];                // exp(trans), rows padded to 12
    __shared__ float Cs[NCHUNK * CPAD];      // chunk matrices, 11 KiB
    __shared__ float Cs2[16 * CPAD];         // tree ping-pong, 5.5 KiB
    __shared__ float rmx_s[16 * 12];
    __shared__ float lgA[32], lgB[16];
    const int T = threadIdx.x;
    const int b = blockIdx.x;
    int len = lengths[b]; if (len < 1) len = 1;

    // ---- phase 0: shared tables ----
    if (T < 81) {
        const int k = T / 9, j = T - 9 * k;
        Pl[k * 12 + j] = __expf(trans[T]);
    }
    #pragma unroll
    for (int r = 0; r < 2; ++r) {
        const int t = T + 384 * r;
        if (t < 512) {
            const int o = eoff(t);
            if (t < len) {
                const float4* p = (const float4*)(em + (size_t)((b << 9) + t) * EMP);
                float4 v0 = p[0], v1 = p[1], v2 = p[2];
                float4 w0 = { __expf(v0.x), __expf(v0.y), __expf(v0.z), __expf(v0.w) };
                float4 w1 = { __expf(v1.x), __expf(v1.y), __expf(v1.z), __expf(v1.w) };
                *(float4*)(eem + o) = w0;
                *(float4*)(eem + o + 4) = w1;
                eem[o + 8] = __expf(v2.x);
            } else {
                const float4 z = { 0.0f, 0.0f, 0.0f, 0.0f };
                *(float4*)(eem + o) = z;
                *(float4*)(eem + o + 4) = z;
                eem[o + 8] = 0.0f;
            }
        }
    }
    __syncthreads();

    // ---- phase 1 ----
    if (T < 144) {
        const int c0 = T / 9;                // 0..15; handles chunks c0, c0+16
        const int i  = T - 9 * c0;
        float A0[9], A1[9];
        #pragma unroll
        for (int j = 0; j < 9; ++j) { A0[j] = (i == j) ? 1.0f : 0.0f; A1[j] = A0[j]; }
        const int ta0 = CH * c0 + 1;
        const int tb0 = ta0 + 256;

        #pragma unroll 1
        for (int s = 0; s < CH; ++s) {
            const int ta = ta0 + s, tb = tb0 + s;
            const int oa = eoff(ta), ob = eoff(tb);
            float4 ea0 = *(const float4*)(eem + oa);
            float4 ea1 = *(const float4*)(eem + oa + 4);
            const float ea8 = eem[oa + 8];
            float4 eb0 = *(const float4*)(eem + ob);
            float4 eb1 = *(const float4*)(eem + ob + 4);
            const float eb8 = eem[ob + 8];
            const float ea[9] = { ea0.x, ea0.y, ea0.z, ea0.w,
                                  ea1.x, ea1.y, ea1.z, ea1.w, ea8 };
            const float eb[9] = { eb0.x, eb0.y, eb0.z, eb0.w,
                                  eb1.x, eb1.y, eb1.z, eb1.w, eb8 };

            float an0[9], an1[9];
            #pragma unroll
            for (int j = 0; j < 9; ++j) { an0[j] = 0.0f; an1[j] = 0.0f; }
            #pragma unroll
            for (int k = 0; k < 9; ++k) {
                float4 p0 = *(const float4*)(Pl + k * 12);
                float4 p1 = *(const float4*)(Pl + k * 12 + 4);
                const float p8 = Pl[k * 12 + 8];
                const float pr[9] = { p0.x, p0.y, p0.z, p0.w,
                                      p1.x, p1.y, p1.z, p1.w, p8 };
                const float a0k = A0[k], a1k = A1[k];
                #pragma unroll
                for (int j = 0; j < 9; ++j) {
                    an0[j] = fmaf(a0k, pr[j], an0[j]);
                    an1[j] = fmaf(a1k, pr[j], an1[j]);
                }
            }
            const bool la = (ta < len), lb = (tb < len);
            #pragma unroll
            for (int j = 0; j < 9; ++j) {
                A0[j] = la ? an0[j] * ea[j] : A0[j];
                A1[j] = lb ? an1[j] * eb[j] : A1[j];
            }
            if (s == 7) {                    // exact 2^-40; constant added at end
                #pragma unroll
                for (int j = 0; j < 9; ++j) { A0[j] *= 0x1p-40f; A1[j] *= 0x1p-40f; }
            }
        }
        #pragma unroll
        for (int j = 0; j < 9; ++j) {
            Cs[c0 * CPAD + i * 9 + j] = A0[j];
            Cs[(c0 + 16) * CPAD + i * 9 + j] = A1[j];
        }
    } else if (T >= 320) {
        // ---- numerator ----
        const int lane = T - 320;
        const int* lab = labels + (size_t)b * S_;
        float part = 0.0f;
        for (int t = 1 + lane; t < len; t += 64) {
            const int tp = lab[t - 1], tc = lab[t];
            part += trans[tp * 9 + tc] + em[(size_t)((b << 9) + t) * EMP + tc];
        }
        #pragma unroll
        for (int off = 32; off >= 1; off >>= 1) part += __shfl_xor(part, off, 64);
        if (lane == 0) {
            const int l0 = lab[0], le = lab[len - 1];
            const float num = start_t[l0] + em[(size_t)(b << 9) * EMP + l0]
                            + part + end_t[le];
            atomicAdd(out, -num);
        }
    }
    if (T < 32) lgA[T] = 0.0f;
    __syncthreads();

    // ---- phase 2a: binary tree product of 32 chunk matrices (5 levels) ----
    float* src = Cs;  float* dst = Cs2;
    float* ls  = lgA; float* ld  = lgB;
    int nn = 16;                             // output nodes this level
    #pragma unroll 1
    for (int lvl = 0; lvl < 5; ++lvl) {
        const int n = T / 9, i = T - 9 * n;
        float row[9];
        if (T < nn * 9) {
            const float* Am = src + (2 * n) * CPAD;
            const float* Bm = src + (2 * n + 1) * CPAD;
            float a[9];
            #pragma unroll
            for (int k = 0; k < 9; ++k) a[k] = Am[i * 9 + k];
            #pragma unroll
            for (int j = 0; j < 9; ++j) row[j] = 0.0f;
            #pragma unroll
            for (int k = 0; k < 9; ++k) {
                const float ak = a[k];
                #pragma unroll
                for (int j = 0; j < 9; ++j)
                    row[j] = fmaf(ak, Bm[k * 9 + j], row[j]);
            }
            float rmx = row[0];
            #pragma unroll
            for (int j = 1; j < 9; ++j) rmx = fmaxf(rmx, row[j]);
            rmx_s[n * 12 + i] = rmx;
        }
        __syncthreads();
        if (T < nn * 9) {
            float mx = rmx_s[n * 12];
            #pragma unroll
            for (int k = 1; k < 9; ++k) mx = fmaxf(mx, rmx_s[n * 12 + k]);
            const float inv = 1.0f / mx;
            #pragma unroll
            for (int j = 0; j < 9; ++j) dst[n * CPAD + i * 9 + j] = row[j] * inv;
            if (i == 0) ld[n] = ls[2 * n] + ls[2 * n + 1] + __logf(mx);
        }
        __syncthreads();
        float* t1 = src; src = dst; dst = t1;
        float* t2 = ls;  ls = ld;  ld = t2;
        nn >>= 1;
    }
    // src = final normalized matrix (node 0), ls[0] = accumulated log

    // ---- phase 2b: apply alpha0 and end transitions ----
    if (T == 0) {
        const float4* e0 = (const float4*)(em + (size_t)(b << 9) * EMP);
        float4 v0 = e0[0], v1 = e0[1], v2 = e0[2];
        float al[9] = { v0.x + start_t[0], v0.y + start_t[1], v0.z + start_t[2],
                        v0.w + start_t[3], v1.x + start_t[4], v1.y + start_t[5],
                        v1.z + start_t[6], v1.w + start_t[7], v2.x + start_t[8] };
        float m0 = al[0];
        #pragma unroll
        for (int j = 1; j < 9; ++j) m0 = fmaxf(m0, al[j]);
        float alpha[9];
        #pragma unroll
        for (int j = 0; j < 9; ++j) alpha[j] = __expf(al[j] - m0);

        float ev = 0.0f;
        #pragma unroll
        for (int j = 0; j < 9; ++j) {
            float s = 0.0f;
            #pragma unroll
            for (int i = 0; i < 9; ++i)
                s = fmaf(alpha[i], src[i * 9 + j], s);
            ev = fmaf(s, __expf(end_t[j]), ev);
        }
        // 32 chunks x 2^-40 scaling -> +1280*ln2 exact constant
        const float den = m0 + ls[0] + __logf(ev)
                        + 1280.0f * 0.6931471805599453f;
        atomicAdd(out, den);
    }
}

// ---------------------------------------------------------------------------
extern "C" void kernel_launch(void* const* d_in, const int* in_sizes, int n_in,
                              void* d_out, int out_size, void* d_ws, size_t ws_size,
                              hipStream_t stream)
{
    (void)in_sizes; (void)n_in; (void)out_size; (void)ws_size;
    const float* hidden  = (const float*)d_in[0];
    const float* W       = (const float*)d_in[1];
    const float* bias    = (const float*)d_in[2];
    const float* start_t = (const float*)d_in[3];
    const float* trans   = (const float*)d_in[4];
    const float* end_t   = (const float*)d_in[5];
    const int*   labels  = (const int*)d_in[6];
    const int*   lengths = (const int*)d_in[7];

    float* em  = (float*)d_ws;               // 64*512*16 floats = 2 MB
    float* out = (float*)d_out;

    emis_kernel<<<512, 256, 0, stream>>>(hidden, W, bias, lengths, em, out);
    crf_kernel<<<B_, 384, 0, stream>>>(em, labels, lengths,
                                       start_t, trans, end_t, out);
}